// Round 1
// baseline (2027.444 us; speedup 1.0000x reference)
//
#include <hip/hip_runtime.h>
#include <stdint.h>

// Problem constants (fixed by the task): x is (B=2, N=8192, D=64) f32, K=16.
constexpr int B_  = 2;
constexpr int N_  = 8192;
constexpr int D_  = 64;
constexpr int K_  = 16;
constexpr int NQ  = B_ * N_;          // 16384 total queries
constexpr int S_  = 16;               // candidate slices (across blocks)
constexpr int J_  = 20;               // top-J margin per slice (> K to absorb f32 noise)
constexpr int SLICE = N_ / S_;        // 512 candidates per slice
constexpr int QPB2  = 256;            // queries per block in scan kernel
constexpr int QPB3  = 32;             // queries per block in rerank kernel
constexpr int SPL   = 8;              // splits per query in rerank (8 x 2 slices x 20 ids = 40 each)

// Sorted ascending top-J insert on packed u64 keys.
// key = (monotone dist bits << 13) | id  -> '<' is (dist, id) lexicographic, ties -> lower id.
template<int JN>
__device__ __forceinline__ void topk_insert(unsigned long long (&key)[JN], unsigned long long nk) {
    if (nk < key[JN - 1]) {
        bool c[JN];
#pragma unroll
        for (int j = 0; j < JN; ++j) c[j] = nk < key[j];
#pragma unroll
        for (int j = JN - 1; j >= 1; --j)
            key[j] = c[j - 1] ? key[j - 1] : (c[j] ? nk : key[j]);
        key[0] = c[0] ? nk : key[0];
    }
}

// K1: squared norms per point, f32.
__global__ void __launch_bounds__(256) norms_k(const float* __restrict__ x, float* __restrict__ nrm) {
    int i = blockIdx.x * 256 + threadIdx.x;           // 0..NQ-1
    const float4* p = reinterpret_cast<const float4*>(x + (size_t)i * D_);
    float a0 = 0.f, a1 = 0.f, a2 = 0.f, a3 = 0.f;
#pragma unroll
    for (int j = 0; j < 16; ++j) {
        float4 v = p[j];
        a0 = fmaf(v.x, v.x, a0); a1 = fmaf(v.y, v.y, a1);
        a2 = fmaf(v.z, v.z, a2); a3 = fmaf(v.w, v.w, a3);
    }
    nrm[i] = (a0 + a1) + (a2 + a3);
}

// K2: f32 scan. Each thread owns one query, scans one slice of 512 candidates,
// keeps top-J as packed u64 keys, writes J candidate ids (u16) to workspace.
// grid = (NQ/QPB2) * S_ = 64 * 16 = 1024 blocks of 256.
__global__ void __launch_bounds__(256, 3) scan_k(const float* __restrict__ x,
                                                 const float* __restrict__ nrm,
                                                 unsigned short* __restrict__ part) {
    int qb = blockIdx.x & 63;          // query block
    int s  = blockIdx.x >> 6;          // slice
    int q  = qb * QPB2 + (int)threadIdx.x;
    int b  = q >> 13;
    int n  = q & (N_ - 1);
    const float* xb = x + (size_t)b * N_ * D_;
    const float4* qp = reinterpret_cast<const float4*>(xb + (size_t)n * D_);
    float4 Q[16];
#pragma unroll
    for (int j = 0; j < 16; ++j) Q[j] = qp[j];

    unsigned long long key[J_];
#pragma unroll
    for (int j = 0; j < J_; ++j) key[j] = ~0ull;

    const float* nb = nrm + b * N_;
    const int m0 = s * SLICE;
    for (int mi = 0; mi < SLICE; ++mi) {
        int m = m0 + mi;
        // Candidate address is block-uniform -> expect scalar (SMEM) loads; L2-resident.
        const float4* cp = reinterpret_cast<const float4*>(xb + (size_t)m * D_);
        float a0 = 0.f, a1 = 0.f, a2 = 0.f, a3 = 0.f;
#pragma unroll
        for (int j = 0; j < 16; ++j) {
            float4 c = cp[j];
            a0 = fmaf(Q[j].x, c.x, a0); a1 = fmaf(Q[j].y, c.y, a1);
            a2 = fmaf(Q[j].z, c.z, a2); a3 = fmaf(Q[j].w, c.w, a3);
        }
        float dot  = (a0 + a1) + (a2 + a3);
        float keyf = fmaf(-2.f, dot, nb[m]);   // s_m - 2*dot : per-query order == full dist order
        // monotone f32 -> u32 (handles negative keys, e.g. the self point at -s_n)
        uint32_t kb = __float_as_uint(keyf);
        kb ^= (uint32_t)((int32_t)kb >> 31) | 0x80000000u;
        unsigned long long nk = ((unsigned long long)kb << 13) | (unsigned)m;
        topk_insert<J_>(key, nk);
    }
    unsigned short* pp = part + ((size_t)q * S_ + s) * J_;
#pragma unroll
    for (int j = 0; j < J_; ++j) pp[j] = (unsigned short)(key[j] & 0x1FFFu);
}

// K3: exact f64 rerank of the 320 surviving candidates per query; exact top-16.
// block = 256 = 32 queries x 8 splits (each split: 2 slices = 40 ids). grid = NQ/32 = 512.
__global__ void __launch_bounds__(256, 3) rerank_k(const float* __restrict__ x,
                                                   const unsigned short* __restrict__ part,
                                                   int* __restrict__ out) {
    __shared__ unsigned long long lds[QPB3 * SPL * K_];   // 32*8*16*8B = 32 KB
    int t  = (int)threadIdx.x;
    int qi = t >> 3;
    int p  = t & 7;
    int q  = blockIdx.x * QPB3 + qi;
    int b  = q >> 13;
    int n  = q & (N_ - 1);
    const float* xb = x + (size_t)b * N_ * D_;
    const float4* qp = reinterpret_cast<const float4*>(xb + (size_t)n * D_);
    float4 Q[16];
#pragma unroll
    for (int j = 0; j < 16; ++j) Q[j] = qp[j];

    unsigned long long key[K_];
#pragma unroll
    for (int j = 0; j < K_; ++j) key[j] = ~0ull;

    const unsigned short* pp = part + ((size_t)q * S_ + p * 2) * J_;  // 2 contiguous slices
    for (int ii = 0; ii < 2 * J_; ++ii) {
        int id = (int)pp[ii];
        const float4* cp = reinterpret_cast<const float4*>(xb + (size_t)id * D_);
        double acc = 0.0;
#pragma unroll
        for (int j = 0; j < 16; ++j) {
            float4 c = cp[j];
            double d0 = (double)Q[j].x - (double)c.x; acc = fma(d0, d0, acc);
            double d1 = (double)Q[j].y - (double)c.y; acc = fma(d1, d1, acc);
            double d2 = (double)Q[j].z - (double)c.z; acc = fma(d2, d2, acc);
            double d3 = (double)Q[j].w - (double)c.w; acc = fma(d3, d3, acc);
        }
        // acc >= 0 exactly -> f64 bits are order-preserving. Low 13 mantissa bits
        // (2^-39 relative) sacrificed for the id; gaps between distinct dists are vastly larger.
        unsigned long long kb = (unsigned long long)__double_as_longlong(acc);
        unsigned long long nk = (kb & ~0x1FFFull) | (unsigned)id;
        topk_insert<K_>(key, nk);
    }

    unsigned long long* lp = lds + ((size_t)qi * SPL + p) * K_;
#pragma unroll
    for (int j = 0; j < K_; ++j) lp[j] = key[j];
    __syncthreads();

    if (p == 0) {
        // merge the other 7 partial lists (u64 compare is exact (dist,id) lexicographic)
        for (int pl = 1; pl < SPL; ++pl) {
            const unsigned long long* sp = lds + ((size_t)qi * SPL + pl) * K_;
            for (int ii = 0; ii < K_; ++ii) topk_insert<K_>(key, sp[ii]);
        }
        int* o1 = out + (size_t)q * K_;                       // nn_idx   [b][n][k]
        int* o2 = out + (size_t)NQ * K_ + (size_t)q * K_;     // center_idx [b][n][k]
#pragma unroll
        for (int kk = 0; kk < K_; ++kk) {
            o1[kk] = (int)(key[kk] & 0x1FFFull);
            o2[kk] = n;
        }
    }
}

extern "C" void kernel_launch(void* const* d_in, const int* in_sizes, int n_in,
                              void* d_out, int out_size, void* d_ws, size_t ws_size,
                              hipStream_t stream) {
    const float* x = (const float*)d_in[0];
    int* out = (int*)d_out;
    float* nrm = (float*)d_ws;                                        // 16384 * 4 B
    unsigned short* part = (unsigned short*)((char*)d_ws + 65536);    // 16384*16*20*2 B ~= 10.5 MB

    hipLaunchKernelGGL(norms_k,  dim3(NQ / 256),        dim3(256), 0, stream, x, nrm);
    hipLaunchKernelGGL(scan_k,   dim3((NQ / QPB2) * S_), dim3(256), 0, stream, x, nrm, part);
    hipLaunchKernelGGL(rerank_k, dim3(NQ / QPB3),       dim3(256), 0, stream, x, part, out);
}

// Round 2
// 918.075 us; speedup vs baseline: 2.2084x; 2.2084x over previous
//
#include <hip/hip_runtime.h>
#include <stdint.h>

// Problem constants (fixed by the task): x is (B=2, N=8192, D=64) f32, K=16.
constexpr int B_  = 2;
constexpr int N_  = 8192;
constexpr int D_  = 64;
constexpr int K_  = 16;
constexpr int NQ  = B_ * N_;          // 16384 total queries
constexpr int S_  = 16;               // candidate slices (across blocks)
constexpr int J_  = 20;               // top-J margin per slice (> K absorbs f32/trunc noise)
constexpr int SLICE = N_ / S_;        // 512 candidates per slice
constexpr int QPB2  = 256;            // queries per block in scan kernel
constexpr int QPB3  = 32;             // queries per block in rerank kernel
constexpr int SPL   = 8;              // splits per query in rerank (8 x 2 slices x 20 ids = 40 each)

// Sorted ascending top-J insert on packed u32 keys.
// key = (monotone f32 bits & ~0x1FFF) | id  -> '<' is (dist, id) lexicographic.
template<int JN>
__device__ __forceinline__ void topk_insert32(uint32_t (&key)[JN], uint32_t nk) {
    if (nk < key[JN - 1]) {
        bool c[JN];
#pragma unroll
        for (int j = 0; j < JN; ++j) c[j] = nk < key[j];
#pragma unroll
        for (int j = JN - 1; j >= 1; --j)
            key[j] = c[j - 1] ? key[j - 1] : (c[j] ? nk : key[j]);
        key[0] = c[0] ? nk : key[0];
    }
}

// u64 variant for the exact f64 rerank.
template<int JN>
__device__ __forceinline__ void topk_insert(unsigned long long (&key)[JN], unsigned long long nk) {
    if (nk < key[JN - 1]) {
        bool c[JN];
#pragma unroll
        for (int j = 0; j < JN; ++j) c[j] = nk < key[j];
#pragma unroll
        for (int j = JN - 1; j >= 1; --j)
            key[j] = c[j - 1] ? key[j - 1] : (c[j] ? nk : key[j]);
        key[0] = c[0] ? nk : key[0];
    }
}

// K1: squared norms per point, f32.
__global__ void __launch_bounds__(256) norms_k(const float* __restrict__ x, float* __restrict__ nrm) {
    int i = blockIdx.x * 256 + threadIdx.x;           // 0..NQ-1
    const float4* p = reinterpret_cast<const float4*>(x + (size_t)i * D_);
    float a0 = 0.f, a1 = 0.f, a2 = 0.f, a3 = 0.f;
#pragma unroll
    for (int j = 0; j < 16; ++j) {
        float4 v = p[j];
        a0 = fmaf(v.x, v.x, a0); a1 = fmaf(v.y, v.y, a1);
        a2 = fmaf(v.z, v.z, a2); a3 = fmaf(v.w, v.w, a3);
    }
    nrm[i] = (a0 + a1) + (a2 + a3);
}

// K2: f32 scan. Thread owns one query; block scans one slice of 512 candidates.
// CRITICAL: batch index b, slice s, and therefore the candidate/norm addresses are
// derived ONLY from blockIdx -> wave-uniform -> compiler emits scalar (SMEM) loads;
// the 64 FMAs read the candidate from SGPR operands. No vector-memory traffic in
// the hot loop (R1 showed per-lane loads of uniform addrs = ~34 TB L2 traffic).
// grid = 64 * 16 = 1024 blocks of 256.
__global__ void __launch_bounds__(256, 4) scan_k(const float* __restrict__ x,
                                                 const float* __restrict__ nrm,
                                                 unsigned short* __restrict__ part) {
    const int qb = blockIdx.x & 63;          // query block (uniform)
    const int s  = blockIdx.x >> 6;          // slice (uniform)
    const int b  = qb >> 5;                  // batch (uniform! 32 query-blocks per batch)
    const int n  = ((qb & 31) << 8) + (int)threadIdx.x;   // query row in batch
    const int q  = (b << 13) + n;

    const float* __restrict__ xb = x + ((size_t)b * N_) * D_;   // uniform base
    const float4* qp = reinterpret_cast<const float4*>(xb + (size_t)n * D_);
    float4 Q[16];
#pragma unroll
    for (int j = 0; j < 16; ++j) Q[j] = qp[j];

    uint32_t key[J_];
#pragma unroll
    for (int j = 0; j < J_; ++j) key[j] = 0xFFFFFFFFu;

    const float* __restrict__ nb = nrm + b * N_;     // uniform base
    const int m0 = s * SLICE;
    for (int mi = 0; mi < SLICE; ++mi) {
        const int m = m0 + mi;                       // uniform
        const float4* __restrict__ cp = reinterpret_cast<const float4*>(xb + (size_t)m * D_);
        float a0 = 0.f, a1 = 0.f, a2 = 0.f, a3 = 0.f;
#pragma unroll
        for (int j = 0; j < 16; ++j) {
            float4 c = cp[j];                        // uniform addr -> s_load, SGPR operand FMAs
            a0 = fmaf(Q[j].x, c.x, a0); a1 = fmaf(Q[j].y, c.y, a1);
            a2 = fmaf(Q[j].z, c.z, a2); a3 = fmaf(Q[j].w, c.w, a3);
        }
        float dot  = (a0 + a1) + (a2 + a3);
        float keyf = fmaf(-2.f, dot, nb[m]);   // s_m - 2*dot : per-query order == full dist order
        // monotone f32 -> u32 (negative keys are common: keyf = dist - s_n)
        uint32_t kb = __float_as_uint(keyf);
        kb ^= (uint32_t)((int32_t)kb >> 31) | 0x80000000u;
        uint32_t nk = (kb & 0xFFFFE000u) | (uint32_t)m;
        topk_insert32<J_>(key, nk);
    }
    unsigned short* pp = part + ((size_t)q * S_ + s) * J_;
#pragma unroll
    for (int j = 0; j < J_; ++j) pp[j] = (unsigned short)(key[j] & 0x1FFFu);
}

// K3: exact f64 rerank of the 320 surviving candidates per query; exact top-16.
// block = 256 = 32 queries x 8 splits (each split: 2 slices = 40 ids). grid = NQ/32 = 512.
__global__ void __launch_bounds__(256, 3) rerank_k(const float* __restrict__ x,
                                                   const unsigned short* __restrict__ part,
                                                   int* __restrict__ out) {
    __shared__ unsigned long long lds[QPB3 * SPL * K_];   // 32*8*16*8B = 32 KB
    int t  = (int)threadIdx.x;
    int qi = t >> 3;
    int p  = t & 7;
    int q  = blockIdx.x * QPB3 + qi;
    int b  = q >> 13;
    int n  = q & (N_ - 1);
    const float* xb = x + (size_t)b * N_ * D_;
    const float4* qp = reinterpret_cast<const float4*>(xb + (size_t)n * D_);
    float4 Q[16];
#pragma unroll
    for (int j = 0; j < 16; ++j) Q[j] = qp[j];

    unsigned long long key[K_];
#pragma unroll
    for (int j = 0; j < K_; ++j) key[j] = ~0ull;

    const unsigned short* pp = part + ((size_t)q * S_ + p * 2) * J_;  // 2 contiguous slices
    for (int ii = 0; ii < 2 * J_; ++ii) {
        int id = (int)pp[ii];
        const float4* cp = reinterpret_cast<const float4*>(xb + (size_t)id * D_);
        double acc = 0.0;
#pragma unroll
        for (int j = 0; j < 16; ++j) {
            float4 c = cp[j];
            double d0 = (double)Q[j].x - (double)c.x; acc = fma(d0, d0, acc);
            double d1 = (double)Q[j].y - (double)c.y; acc = fma(d1, d1, acc);
            double d2 = (double)Q[j].z - (double)c.z; acc = fma(d2, d2, acc);
            double d3 = (double)Q[j].w - (double)c.w; acc = fma(d3, d3, acc);
        }
        // acc >= 0 exactly -> f64 bits order-preserving. Low 13 mantissa bits
        // (2^-39 relative) sacrificed for the id; true gaps are vastly larger.
        unsigned long long kb = (unsigned long long)__double_as_longlong(acc);
        unsigned long long nk = (kb & ~0x1FFFull) | (unsigned)id;
        topk_insert<K_>(key, nk);
    }

    unsigned long long* lp = lds + ((size_t)qi * SPL + p) * K_;
#pragma unroll
    for (int j = 0; j < K_; ++j) lp[j] = key[j];
    __syncthreads();

    if (p == 0) {
        // merge the other 7 partial lists (u64 compare is exact (dist,id) lexicographic)
        for (int pl = 1; pl < SPL; ++pl) {
            const unsigned long long* sp = lds + ((size_t)qi * SPL + pl) * K_;
            for (int ii = 0; ii < K_; ++ii) topk_insert<K_>(key, sp[ii]);
        }
        int* o1 = out + (size_t)q * K_;                       // nn_idx    [b][n][k]
        int* o2 = out + (size_t)NQ * K_ + (size_t)q * K_;     // center_idx[b][n][k]
#pragma unroll
        for (int kk = 0; kk < K_; ++kk) {
            o1[kk] = (int)(key[kk] & 0x1FFFull);
            o2[kk] = n;
        }
    }
}

extern "C" void kernel_launch(void* const* d_in, const int* in_sizes, int n_in,
                              void* d_out, int out_size, void* d_ws, size_t ws_size,
                              hipStream_t stream) {
    const float* x = (const float*)d_in[0];
    int* out = (int*)d_out;
    float* nrm = (float*)d_ws;                                        // 16384 * 4 B
    unsigned short* part = (unsigned short*)((char*)d_ws + 65536);    // 16384*16*20*2 B ~= 10.5 MB

    hipLaunchKernelGGL(norms_k,  dim3(NQ / 256),         dim3(256), 0, stream, x, nrm);
    hipLaunchKernelGGL(scan_k,   dim3((NQ / QPB2) * S_), dim3(256), 0, stream, x, nrm, part);
    hipLaunchKernelGGL(rerank_k, dim3(NQ / QPB3),        dim3(256), 0, stream, x, part, out);
}